// Round 15
// baseline (83.499 us; speedup 1.0000x reference)
//
#include <hip/hip_runtime.h>

#define NQ 10
#define NG 4
#define QD 6
#define NBATCH 1024

// 2^10 = 1024 amps; 64 lanes x 16 amps/lane. One WAVE = one REAL COMPONENT
// (re or im) of one circuit (tangent-form layers are real; R10/R13-validated).
// 8192 waves -> 32 waves/CU. Init computed once by the even wave, im shipped
// via LDS (R13). Expectations couple re+im partials via 128 B LDS.
// Flat index i: bit p (LSB) <-> wire q = 9-p (wire 0 = MSB, PennyLane order).
// Layout A only: reg bits 0..3 <- amp bits 0..3, lane bits 0..5 <- amp 4..9.
// R15: pipe REbalance. R14 ledger at 32 waves/CU: LDS pipe ~465 ops/wave
// ~37 us (the wall), VALU ~11 us. So xor4/xor8 go back to VALU-DPP
// (row_ror:8 single op, half-mirror+quad-rev 2 ops — R6/R9-validated),
// keeping only xor16 (ds_swizzle) + xor32 (bpermute) on the LDS pipe:
//   xor1/xor2  = quad_perm DPP (fuses into v_fmac_dpp, ~free)   [VALU]
//   xor4       = dpp 0x141 then 0x1B (outer fuses)              [VALU]
//   xor8       = dpp row_ror:8 (fuses)                          [VALU]
//   xor16      = ds_swizzle 0x401F                              [LDS]
//   xor32      = __shfl_xor -> ds_bpermute                      [LDS]
// tan-form rotations + global scale (R9), CZ sign-bit xor layout-A masks.

typedef unsigned u2v __attribute__((ext_vector_type(2)));

// ---------- DPP helpers ----------
template<int CTRL, int RM, int BM, bool BC>
__device__ __forceinline__ float dppmov(float x) {
    return __int_as_float(__builtin_amdgcn_update_dpp(
        0, __float_as_int(x), CTRL, RM, BM, BC));
}
template<int CTRL>
__device__ __forceinline__ float dpp1(float x) { return dppmov<CTRL,0xF,0xF,true>(x); }

template<int PAT>
__device__ __forceinline__ float swz(float x) {
    return __int_as_float(__builtin_amdgcn_ds_swizzle(__float_as_int(x), PAT));
}

struct FX1 { static __device__ __forceinline__ float f(float x){ return dpp1<0xB1>(x); } };
struct FX2 { static __device__ __forceinline__ float f(float x){ return dpp1<0x4E>(x); } };
struct FX4 { static __device__ __forceinline__ float f(float x){ return dpp1<0x1B>(dpp1<0x141>(x)); } };
struct FX8 { static __device__ __forceinline__ float f(float x){ return dpp1<0x128>(x); } };
struct FX16{ static __device__ __forceinline__ float f(float x){ return swz<0x401F>(x); } };
struct FX32{ static __device__ __forceinline__ float f(float x){ return __shfl_xor(x, 32, 64); } };

__device__ __forceinline__ float rlane(float v, int idx) {
    return __int_as_float(__builtin_amdgcn_readlane(__float_as_int(v), idx));
}

// wave-wide sum broadcast (validated R3..R14)
__device__ __forceinline__ float wave_reduce(float x) {
    x += dppmov<0x111,0xF,0xF,true >(x);
    x += dppmov<0x112,0xF,0xF,true >(x);
    x += dppmov<0x114,0xF,0xF,true >(x);
    x += dppmov<0x118,0xF,0xF,true >(x);
    x += dppmov<0x142,0xA,0xF,false>(x);
    x += dppmov<0x143,0xC,0xF,false>(x);
    return __int_as_float(__builtin_amdgcn_readlane(__float_as_int(x), 63));
}

// wave-wide product (R9-validated)
__device__ __forceinline__ float wave_product(float x) {
    x *= dpp1<0xB1>(x);
    x *= dpp1<0x4E>(x);
    x *= FX4::f(x);
    x *= FX8::f(x);
    x *= FX16::f(x);
    x *= FX32::f(x);
    return x;
}

// (I - t*J) intra-register pair (R9-validated)
template<int M>
__device__ __forceinline__ void intra1(float (&s)[16], float t) {
#pragma unroll
    for (int j = 0; j < 16; ++j)
        if ((j & M) == 0) {
            const int k = j | M;
            float v0 = s[j], v1 = s[k];
            s[j] = fmaf(-t, v1, v0);
            s[k] = fmaf( t, v0, v1);
        }
}

// (I - t*J) cross-lane (sign convention validated R1..R14)
template<class PF, int LM>
__device__ __forceinline__ void cross1(float (&s)[16], float t, int lane) {
    const float sv = (lane & LM) ? t : -t;
#pragma unroll
    for (int j = 0; j < 16; ++j)
        s[j] = fmaf(PF::f(s[j]), sv, s[j]);
}

template<class PF>
__device__ __forceinline__ float cross_exp1(const float (&s)[16]) {
    float a = 0.f;
#pragma unroll
    for (int j = 0; j < 16; ++j)
        a = fmaf(PF::f(s[j]), s[j], a);
    return a;
}

template<int M>
__device__ __forceinline__ float intra_exp1(const float (&s)[16]) {
    float a = 0.f;
#pragma unroll
    for (int j = 0; j < 16; ++j)
        a += s[j] * s[j ^ M];
    return a;
}

__global__ __launch_bounds__(256, 2) void qsim_kernel(
    const float* __restrict__ noise,     // (NBATCH, NQ)
    const float* __restrict__ qp,        // (NG, QD, NQ)
    float* __restrict__ out)             // (NBATCH, NG*NQ)
{
    __shared__ float ship[2][1024];      // im half of init state per circuit
    __shared__ float partlds[2][16];     // re-wave expectation partials

    const int wave = threadIdx.x >> 6;
    const int lane = threadIdx.x & 63;
    const int pc   = wave >> 1;                       // circuit within block
    const int comp = wave & 1;                        // 0 = re, 1 = im
    const int g    = blockIdx.x & 3;                  // block-uniform
    const int b    = (blockIdx.x >> 2) * 2 + pc;      // batch index

    // ---- weights: lane-parallel sincos once; t = tan, scale2 = prod(c)^2 ----
    float wt, scale2;
    {
        const int widx = (lane < QD * NQ) ? lane : 0;
        float sv, cv;
        __sincosf(0.5f * qp[g * (QD * NQ) + widx], &sv, &cv);
        wt = sv / cv;
        float cvc = (lane < QD * NQ) ? cv : 1.0f;
        float p = wave_product(cvc);
        scale2 = p * p;
    }

    // ---- init: even wave computes complex product state, ships im via LDS ----
    float s[16];
    if (comp == 0) {
        float nc[NQ], ns[NQ];
#pragma unroll
        for (int q = 0; q < NQ; ++q)
            __sincosf(0.5f * noise[b * NQ + q], &ns[q], &nc[q]);

        auto facr = [&](int q, int bit) { return bit ? nc[q]*ns[q] : nc[q]*nc[q]; };
        auto faci = [&](int q, int bit) { return bit ? -nc[q]*ns[q] : -ns[q]*ns[q]; };

        float hr = 1.f, hi = 0.f;
#pragma unroll
        for (int p = 4; p <= 9; ++p) {
            const int q = NQ - 1 - p, bit = (lane >> (p - 4)) & 1;
            float fr = facr(q, bit), fi = faci(q, bit);
            float tr = hr * fr - hi * fi;
            float ti = hr * fi + hi * fr;
            hr = tr; hi = ti;
        }
        float t01r[4], t01i[4], t23r[4], t23i[4];
#pragma unroll
        for (int a = 0; a < 4; ++a) {
            float f9r = facr(9, a & 1), f9i = faci(9, a & 1);
            float f8r = facr(8, (a >> 1) & 1), f8i = faci(8, (a >> 1) & 1);
            t01r[a] = f9r * f8r - f9i * f8i;
            t01i[a] = f9r * f8i + f9i * f8r;
            float f7r = facr(7, a & 1), f7i = faci(7, a & 1);
            float f6r = facr(6, (a >> 1) & 1), f6i = faci(6, (a >> 1) & 1);
            t23r[a] = f7r * f6r - f7i * f6i;
            t23i[a] = f7r * f6i + f7i * f6r;
        }
        float prer[4], prei[4];
#pragma unroll
        for (int a = 0; a < 4; ++a) {
            prer[a] = hr * t01r[a] - hi * t01i[a];
            prei[a] = hr * t01i[a] + hi * t01r[a];
        }
#pragma unroll
        for (int j = 0; j < 16; ++j) {
            s[j] = prer[j & 3] * t23r[j >> 2] - prei[j & 3] * t23i[j >> 2];
            float ii = prer[j & 3] * t23i[j >> 2] + prei[j & 3] * t23r[j >> 2];
            ship[pc][j * 64 + lane] = ii;   // conflict-free (stride-1 per lane)
        }
    }
    __syncthreads();
    if (comp == 1) {
#pragma unroll
        for (int j = 0; j < 16; ++j) s[j] = ship[pc][j * 64 + lane];
    }

    // ---- CZ sign masks, layout A (R9/R12-validated parity decomposition) ----
    unsigned aE, aO;
    {
        unsigned parA = (unsigned)(__popc(lane & (lane >> 1)) & 1) << 31;
        aE = parA;                                     // j < 8
        aO = parA ^ ((unsigned)(lane & 1) << 31);      // j >= 8 (pair j3,l0)
    }
    auto czA = [&](float (&v)[16]) {
#pragma unroll
        for (int j = 0; j < 16; ++j) {
            const bool jp = (__popc(j & (j >> 1)) & 1) != 0;         // compile-time
            const unsigned base = (j & 8) ? aO : aE;
            const unsigned m = jp ? (base ^ 0x80000000u) : base;
            v[j] = __uint_as_float(__float_as_uint(v[j]) ^ m);
        }
    };

    // ---- QD layers: layout A throughout; LDS pipe only for xor16/xor32 ----
#pragma unroll 1
    for (int l = 0; l < QD; ++l) {
        float t[NQ];
#pragma unroll
        for (int q = 0; q < NQ; ++q) t[q] = rlane(wt, l * NQ + q);

        // LDS-pipe wires first so swizzle/bpermute issue early; RY on distinct
        // wires commute exactly, so order is free.
        cross1<FX16,16>(s, t[1], lane);          // wire 1 (lane bit 4)  [LDS]
        cross1<FX32,32>(s, t[0], lane);          // wire 0 (lane bit 5)  [LDS]
        intra1<1>(s, t[9]);                      // wires 9..6 (reg bits)
        intra1<2>(s, t[8]);
        intra1<4>(s, t[7]);
        intra1<8>(s, t[6]);
        cross1<FX1, 1>(s, t[5], lane);           // wire 5 (lane bit 0)  [DPP]
        cross1<FX2, 2>(s, t[4], lane);           // wire 4 (lane bit 1)  [DPP]
        cross1<FX4, 4>(s, t[3], lane);           // wire 3 (lane bit 2)  [DPP x2]
        cross1<FX8, 8>(s, t[2], lane);           // wire 2 (lane bit 3)  [DPP ror8]
        czA(s);
    }

    // ---- expectations: this component's partial sums ----
    float myp = 0.f;
    {
        float e9 = wave_reduce(intra_exp1<1>(s));
        float e8 = wave_reduce(intra_exp1<2>(s));
        float e7 = wave_reduce(intra_exp1<4>(s));
        float e6 = wave_reduce(intra_exp1<8>(s));
        float e5 = wave_reduce(cross_exp1<FX1>(s));
        float e4 = wave_reduce(cross_exp1<FX2>(s));
        float e3 = wave_reduce(cross_exp1<FX4>(s));
        float e2 = wave_reduce(cross_exp1<FX8>(s));
        float e1 = wave_reduce(cross_exp1<FX16>(s));
        float e0 = wave_reduce(cross_exp1<FX32>(s));
        myp = (lane == 0) ? e0 : myp;
        myp = (lane == 1) ? e1 : myp;
        myp = (lane == 2) ? e2 : myp;
        myp = (lane == 3) ? e3 : myp;
        myp = (lane == 4) ? e4 : myp;
        myp = (lane == 5) ? e5 : myp;
        myp = (lane == 6) ? e6 : myp;
        myp = (lane == 7) ? e7 : myp;
        myp = (lane == 8) ? e8 : myp;
        myp = (lane == 9) ? e9 : myp;
    }

    // ---- couple re+im partials via LDS; im wave stores (R13-validated) ----
    if (comp == 0 && lane < NQ) partlds[pc][lane] = myp;
    __syncthreads();
    if (comp == 1 && lane < NQ)
        out[b * (NG * NQ) + g * NQ + lane] = (myp + partlds[pc][lane]) * scale2;
}

extern "C" void kernel_launch(void* const* d_in, const int* in_sizes, int n_in,
                              void* d_out, int out_size, void* d_ws, size_t ws_size,
                              hipStream_t stream) {
    const float* noise = (const float*)d_in[0];   // (1024, 10) float32
    const float* qp    = (const float*)d_in[1];   // (4, 6, 10) float32
    float* out = (float*)d_out;                   // (1024, 40) float32

    const int nblocks = (NBATCH * NG) / 2;        // 2048 blocks x 4 waves
    qsim_kernel<<<nblocks, 256, 0, stream>>>(noise, qp, out);
}

// Round 16
// 82.368 us; speedup vs baseline: 1.0137x; 1.0137x over previous
//
#include <hip/hip_runtime.h>

#define NQ 10
#define NG 4
#define QD 6
#define NBATCH 1024

// FINAL (R14 config — best measured: wall 82.0 us, kernel est ~33 us).
// 2^10 = 1024 amps; 64 lanes x 16 amps/lane. One WAVE = one REAL COMPONENT
// (re or im) of one circuit (tangent-form layers are real; R10/R13-validated).
// 8192 waves -> 32 waves/CU. Init computed once by the even wave, im shipped
// via LDS (R13-validated). Expectations couple re+im partials via 128 B LDS.
// Flat index i: bit p (LSB) <-> wire q = 9-p (wire 0 = MSB, PennyLane order).
// Layout A only: reg bits 0..3 <- amp bits 0..3, lane bits 0..5 <- amp 4..9.
// Fetch placement (R12/R14-validated; R15's DPP-rebalance regressed):
//   xor1/xor2  = quad_perm DPP (fuses into v_fmac_dpp)           [VALU]
//   xor4/8/16  = ds_swizzle BitMode                              [LDS pipe]
//   xor32      = __shfl_xor -> ds_bpermute                       [LDS pipe]
// tan-form rotations + global scale (R9), CZ sign-bit xor layout-A masks.
// Session ledger: 73 us (R1 naive-shfl) -> 55 (DPP, R3) -> 51 (R4) ->
// 39.5 (tan-form, R9) -> ~37 (swizzle offload, R12) -> ~35 (re/im split,
// R13) -> ~33 (R14). Three pipe-balance variants (R13/R14/R15) within
// +-1 us => latency/issue-bound plateau of this structure.

typedef unsigned u2v __attribute__((ext_vector_type(2)));

// ---------- DPP helpers ----------
template<int CTRL, int RM, int BM, bool BC>
__device__ __forceinline__ float dppmov(float x) {
    return __int_as_float(__builtin_amdgcn_update_dpp(
        0, __float_as_int(x), CTRL, RM, BM, BC));
}
template<int CTRL>
__device__ __forceinline__ float dpp1(float x) { return dppmov<CTRL,0xF,0xF,true>(x); }

template<int PAT>
__device__ __forceinline__ float swz(float x) {
    return __int_as_float(__builtin_amdgcn_ds_swizzle(__float_as_int(x), PAT));
}

struct FX1 { static __device__ __forceinline__ float f(float x){ return dpp1<0xB1>(x); } };
struct FX2 { static __device__ __forceinline__ float f(float x){ return dpp1<0x4E>(x); } };
struct FX4 { static __device__ __forceinline__ float f(float x){ return swz<0x101F>(x); } };
struct FX8 { static __device__ __forceinline__ float f(float x){ return swz<0x201F>(x); } };
struct FX16{ static __device__ __forceinline__ float f(float x){ return swz<0x401F>(x); } };
struct FX32{ static __device__ __forceinline__ float f(float x){ return __shfl_xor(x, 32, 64); } };

__device__ __forceinline__ float rlane(float v, int idx) {
    return __int_as_float(__builtin_amdgcn_readlane(__float_as_int(v), idx));
}

// wave-wide sum broadcast (validated R3..R15)
__device__ __forceinline__ float wave_reduce(float x) {
    x += dppmov<0x111,0xF,0xF,true >(x);
    x += dppmov<0x112,0xF,0xF,true >(x);
    x += dppmov<0x114,0xF,0xF,true >(x);
    x += dppmov<0x118,0xF,0xF,true >(x);
    x += dppmov<0x142,0xA,0xF,false>(x);
    x += dppmov<0x143,0xC,0xF,false>(x);
    return __int_as_float(__builtin_amdgcn_readlane(__float_as_int(x), 63));
}

// wave-wide product (R9-validated)
__device__ __forceinline__ float wave_product(float x) {
    x *= dpp1<0xB1>(x);
    x *= dpp1<0x4E>(x);
    x *= FX4::f(x);
    x *= FX8::f(x);
    x *= FX16::f(x);
    x *= FX32::f(x);
    return x;
}

// (I - t*J) intra-register pair (R9-validated)
template<int M>
__device__ __forceinline__ void intra1(float (&s)[16], float t) {
#pragma unroll
    for (int j = 0; j < 16; ++j)
        if ((j & M) == 0) {
            const int k = j | M;
            float v0 = s[j], v1 = s[k];
            s[j] = fmaf(-t, v1, v0);
            s[k] = fmaf( t, v0, v1);
        }
}

// (I - t*J) cross-lane (sign convention validated R1..R15)
template<class PF, int LM>
__device__ __forceinline__ void cross1(float (&s)[16], float t, int lane) {
    const float sv = (lane & LM) ? t : -t;
#pragma unroll
    for (int j = 0; j < 16; ++j)
        s[j] = fmaf(PF::f(s[j]), sv, s[j]);
}

template<class PF>
__device__ __forceinline__ float cross_exp1(const float (&s)[16]) {
    float a = 0.f;
#pragma unroll
    for (int j = 0; j < 16; ++j)
        a = fmaf(PF::f(s[j]), s[j], a);
    return a;
}

template<int M>
__device__ __forceinline__ float intra_exp1(const float (&s)[16]) {
    float a = 0.f;
#pragma unroll
    for (int j = 0; j < 16; ++j)
        a += s[j] * s[j ^ M];
    return a;
}

__global__ __launch_bounds__(256, 2) void qsim_kernel(
    const float* __restrict__ noise,     // (NBATCH, NQ)
    const float* __restrict__ qp,        // (NG, QD, NQ)
    float* __restrict__ out)             // (NBATCH, NG*NQ)
{
    __shared__ float ship[2][1024];      // im half of init state per circuit
    __shared__ float partlds[2][16];     // re-wave expectation partials

    const int wave = threadIdx.x >> 6;
    const int lane = threadIdx.x & 63;
    const int pc   = wave >> 1;                       // circuit within block
    const int comp = wave & 1;                        // 0 = re, 1 = im
    const int g    = blockIdx.x & 3;                  // block-uniform
    const int b    = (blockIdx.x >> 2) * 2 + pc;      // batch index

    // ---- weights: lane-parallel sincos once; t = tan, scale2 = prod(c)^2 ----
    float wt, scale2;
    {
        const int widx = (lane < QD * NQ) ? lane : 0;
        float sv, cv;
        __sincosf(0.5f * qp[g * (QD * NQ) + widx], &sv, &cv);
        wt = sv / cv;
        float cvc = (lane < QD * NQ) ? cv : 1.0f;
        float p = wave_product(cvc);
        scale2 = p * p;
    }

    // ---- init: even wave computes complex product state, ships im via LDS ----
    float s[16];
    if (comp == 0) {
        float nc[NQ], ns[NQ];
#pragma unroll
        for (int q = 0; q < NQ; ++q)
            __sincosf(0.5f * noise[b * NQ + q], &ns[q], &nc[q]);

        auto facr = [&](int q, int bit) { return bit ? nc[q]*ns[q] : nc[q]*nc[q]; };
        auto faci = [&](int q, int bit) { return bit ? -nc[q]*ns[q] : -ns[q]*ns[q]; };

        float hr = 1.f, hi = 0.f;
#pragma unroll
        for (int p = 4; p <= 9; ++p) {
            const int q = NQ - 1 - p, bit = (lane >> (p - 4)) & 1;
            float fr = facr(q, bit), fi = faci(q, bit);
            float tr = hr * fr - hi * fi;
            float ti = hr * fi + hi * fr;
            hr = tr; hi = ti;
        }
        float t01r[4], t01i[4], t23r[4], t23i[4];
#pragma unroll
        for (int a = 0; a < 4; ++a) {
            float f9r = facr(9, a & 1), f9i = faci(9, a & 1);
            float f8r = facr(8, (a >> 1) & 1), f8i = faci(8, (a >> 1) & 1);
            t01r[a] = f9r * f8r - f9i * f8i;
            t01i[a] = f9r * f8i + f9i * f8r;
            float f7r = facr(7, a & 1), f7i = faci(7, a & 1);
            float f6r = facr(6, (a >> 1) & 1), f6i = faci(6, (a >> 1) & 1);
            t23r[a] = f7r * f6r - f7i * f6i;
            t23i[a] = f7r * f6i + f7i * f6r;
        }
        float prer[4], prei[4];
#pragma unroll
        for (int a = 0; a < 4; ++a) {
            prer[a] = hr * t01r[a] - hi * t01i[a];
            prei[a] = hr * t01i[a] + hi * t01r[a];
        }
#pragma unroll
        for (int j = 0; j < 16; ++j) {
            s[j] = prer[j & 3] * t23r[j >> 2] - prei[j & 3] * t23i[j >> 2];
            float ii = prer[j & 3] * t23i[j >> 2] + prei[j & 3] * t23r[j >> 2];
            ship[pc][j * 64 + lane] = ii;   // conflict-free (stride-1 per lane)
        }
    }
    __syncthreads();
    if (comp == 1) {
#pragma unroll
        for (int j = 0; j < 16; ++j) s[j] = ship[pc][j * 64 + lane];
    }

    // ---- CZ sign masks, layout A (R9/R12-validated parity decomposition) ----
    unsigned aE, aO;
    {
        unsigned parA = (unsigned)(__popc(lane & (lane >> 1)) & 1) << 31;
        aE = parA;                                     // j < 8
        aO = parA ^ ((unsigned)(lane & 1) << 31);      // j >= 8 (pair j3,l0)
    }
    auto czA = [&](float (&v)[16]) {
#pragma unroll
        for (int j = 0; j < 16; ++j) {
            const bool jp = (__popc(j & (j >> 1)) & 1) != 0;         // compile-time
            const unsigned base = (j & 8) ? aO : aE;
            const unsigned m = jp ? (base ^ 0x80000000u) : base;
            v[j] = __uint_as_float(__float_as_uint(v[j]) ^ m);
        }
    };

    // ---- QD layers: layout A throughout; LDS-pipe fetches for xor4..32 ----
#pragma unroll 1
    for (int l = 0; l < QD; ++l) {
        float t[NQ];
#pragma unroll
        for (int q = 0; q < NQ; ++q) t[q] = rlane(wt, l * NQ + q);

        // LDS-pipe wires first so swizzles issue early; RY on distinct wires
        // commute exactly, so order is free.
        cross1<FX4, 4>(s, t[3], lane);           // wire 3 (lane bit 2)  [LDS]
        cross1<FX8, 8>(s, t[2], lane);           // wire 2 (lane bit 3)  [LDS]
        cross1<FX16,16>(s, t[1], lane);          // wire 1 (lane bit 4)  [LDS]
        cross1<FX32,32>(s, t[0], lane);          // wire 0 (lane bit 5)  [LDS]
        intra1<1>(s, t[9]);                      // wires 9..6 (reg bits)
        intra1<2>(s, t[8]);
        intra1<4>(s, t[7]);
        intra1<8>(s, t[6]);
        cross1<FX1, 1>(s, t[5], lane);           // wire 5 (lane bit 0)  [DPP]
        cross1<FX2, 2>(s, t[4], lane);           // wire 4 (lane bit 1)  [DPP]
        czA(s);
    }

    // ---- expectations: this component's partial sums ----
    float myp = 0.f;
    {
        float e9 = wave_reduce(intra_exp1<1>(s));
        float e8 = wave_reduce(intra_exp1<2>(s));
        float e7 = wave_reduce(intra_exp1<4>(s));
        float e6 = wave_reduce(intra_exp1<8>(s));
        float e5 = wave_reduce(cross_exp1<FX1>(s));
        float e4 = wave_reduce(cross_exp1<FX2>(s));
        float e3 = wave_reduce(cross_exp1<FX4>(s));
        float e2 = wave_reduce(cross_exp1<FX8>(s));
        float e1 = wave_reduce(cross_exp1<FX16>(s));
        float e0 = wave_reduce(cross_exp1<FX32>(s));
        myp = (lane == 0) ? e0 : myp;
        myp = (lane == 1) ? e1 : myp;
        myp = (lane == 2) ? e2 : myp;
        myp = (lane == 3) ? e3 : myp;
        myp = (lane == 4) ? e4 : myp;
        myp = (lane == 5) ? e5 : myp;
        myp = (lane == 6) ? e6 : myp;
        myp = (lane == 7) ? e7 : myp;
        myp = (lane == 8) ? e8 : myp;
        myp = (lane == 9) ? e9 : myp;
    }

    // ---- couple re+im partials via LDS; im wave stores (R13-validated) ----
    if (comp == 0 && lane < NQ) partlds[pc][lane] = myp;
    __syncthreads();
    if (comp == 1 && lane < NQ)
        out[b * (NG * NQ) + g * NQ + lane] = (myp + partlds[pc][lane]) * scale2;
}

extern "C" void kernel_launch(void* const* d_in, const int* in_sizes, int n_in,
                              void* d_out, int out_size, void* d_ws, size_t ws_size,
                              hipStream_t stream) {
    const float* noise = (const float*)d_in[0];   // (1024, 10) float32
    const float* qp    = (const float*)d_in[1];   // (4, 6, 10) float32
    float* out = (float*)d_out;                   // (1024, 40) float32

    const int nblocks = (NBATCH * NG) / 2;        // 2048 blocks x 4 waves
    qsim_kernel<<<nblocks, 256, 0, stream>>>(noise, qp, out);
}